// Round 1
// 879.229 us; speedup vs baseline: 1.1607x; 1.1607x over previous
//
#include <hip/hip_runtime.h>
#include <hip/hip_bf16.h>

// Problem constants (fixed by setup_inputs)
#define BB 1024
#define SS 1024
#define DIN 128
#define DSLOT 64
#define TOPK 8
#define TOKENS (BB*SS)          // 1048576
#define TM 128                  // tokens per block in MLP kernel

// ---- bf16 helpers (manual, RNE) ----
__device__ __forceinline__ unsigned short f2bf(float x) {
    unsigned u = __float_as_uint(x);
    return (unsigned short)((u + 0x7fffu + ((u >> 16) & 1u)) >> 16);
}
__device__ __forceinline__ float bf2f(unsigned u16) {
    return __uint_as_float(u16 << 16);
}

// ------------------------------------------------------------------
// prep: v[d] = sum_j W2[d][j] * qmean[j],  qmean[j] = (q0[j]+q1[j])*0.5*0.125
//       vv[64] = sum_j b2[j]*qmean[j]
// ------------------------------------------------------------------
__global__ void prep_kernel(const float* __restrict__ W2, const float* __restrict__ b2,
                            const float* __restrict__ q, float* __restrict__ vv) {
    __shared__ float qm[64];
    int d = threadIdx.x;
    if (d < 64) qm[d] = (q[d] + q[64 + d]) * 0.0625f; // 0.5 (head mean) * 0.125 (1/sqrt(64))
    __syncthreads();
    if (d < 64) {
        float acc = 0.f;
        #pragma unroll
        for (int j = 0; j < 64; ++j) acc = fmaf(W2[d * 64 + j], qm[j], acc);
        vv[d] = acc;
    }
    if (d == 0) {
        float c = 0.f;
        for (int j = 0; j < 64; ++j) c = fmaf(b2[j], qm[j], c);
        vv[64] = c;
    }
}

// ------------------------------------------------------------------
// Layer-1 only: h = relu(X@W1 + b1), scores from the fp32 register path
// (bit-identical expressions to the passing baseline -> identical top-k),
// h stored bf16 to workspace. Layer-2 is algebraically deferred:
//   ctx = (sum_s w_s h_s)@W2 + b2,  sel = h_sel@W2 + b2  (done in attn).
// ------------------------------------------------------------------
__global__ __launch_bounds__(256, 5) void mlp_kernel(
    const float* __restrict__ feats, const float* __restrict__ W1,
    const float* __restrict__ b1, const float* __restrict__ vv,
    unsigned short* __restrict__ hws, float* __restrict__ scores)
{
    __shared__ float Xs[TM][33];              // stride 33: conflict-free column reads
    __shared__ float W1s[32][64];
    __shared__ float vS[64], b1s[64];
    __shared__ float c0s;

    const int tid = threadIdx.x;
    const int tx = tid & 3;            // channel group: d0 = 16*tx
    const int ty = tid >> 2;           // token pair: tokens 2*ty, 2*ty+1
    const int d0 = tx * 16;
    const long t0 = (long)blockIdx.x * TM;

    if (tid < 64) { vS[tid] = vv[tid]; b1s[tid] = b1[tid]; }
    if (tid == 0) c0s = vv[64];

    float acc1[2][16];
    #pragma unroll
    for (int t = 0; t < 2; ++t)
        #pragma unroll
        for (int j = 0; j < 16; ++j) acc1[t][j] = 0.f;

    // ---- layer 1: K = 128 in 4 chunks of 32 ----
    for (int kc = 0; kc < 4; ++kc) {
        __syncthreads();   // protect Xs/W1s from previous chunk readers
        // stage Xs: 128 rows x 32 floats = 1024 float4, 4 per thread
        #pragma unroll
        for (int i = 0; i < 4; ++i) {
            int li = tid + i * 256;
            int row = li >> 3, c4 = li & 7;
            float4 f = *(const float4*)&feats[(t0 + row) * DIN + kc * 32 + c4 * 4];
            Xs[row][c4 * 4 + 0] = f.x; Xs[row][c4 * 4 + 1] = f.y;
            Xs[row][c4 * 4 + 2] = f.z; Xs[row][c4 * 4 + 3] = f.w;
        }
        // stage W1 chunk: 32 x 64 = 512 float4, 2 per thread
        #pragma unroll
        for (int i = 0; i < 2; ++i) {
            int li = tid + i * 256;
            int row = li >> 4, c4 = li & 15;
            *(float4*)&W1s[row][c4 * 4] = *(const float4*)&W1[(kc * 32 + row) * DSLOT + c4 * 4];
        }
        __syncthreads();
        #pragma unroll 8
        for (int kk = 0; kk < 32; ++kk) {
            float w[16];
            *(float4*)&w[0]  = *(const float4*)&W1s[kk][d0];
            *(float4*)&w[4]  = *(const float4*)&W1s[kk][d0 + 4];
            *(float4*)&w[8]  = *(const float4*)&W1s[kk][d0 + 8];
            *(float4*)&w[12] = *(const float4*)&W1s[kk][d0 + 12];
            float x0 = Xs[2 * ty + 0][kk];
            float x1 = Xs[2 * ty + 1][kk];
            #pragma unroll
            for (int j = 0; j < 16; ++j) {
                acc1[0][j] = fmaf(x0, w[j], acc1[0][j]);
                acc1[1][j] = fmaf(x1, w[j], acc1[1][j]);
            }
        }
    }

    // bias + relu (fp32 registers)
    float h[2][16];
    #pragma unroll
    for (int t = 0; t < 2; ++t)
        #pragma unroll
        for (int j = 0; j < 16; ++j) h[t][j] = fmaxf(acc1[t][j] + b1s[d0 + j], 0.f);

    // scores from the fp32 register path: hidden . v + c0, reduce over 4 tx lanes
    // (identical expressions/order to baseline -> identical top-k ordering)
    float p0 = 0.f, p1 = 0.f;
    #pragma unroll
    for (int j = 0; j < 16; ++j) {
        p0 = fmaf(h[0][j], vS[d0 + j], p0);
        p1 = fmaf(h[1][j], vS[d0 + j], p1);
    }
    p0 += __shfl_xor(p0, 1); p0 += __shfl_xor(p0, 2);
    p1 += __shfl_xor(p1, 1); p1 += __shfl_xor(p1, 2);
    if (tx == 0) {
        scores[t0 + 2 * ty + 0] = p0 + c0s;
        scores[t0 + 2 * ty + 1] = p1 + c0s;
    }

    // store h as bf16 (2 x uint4 per token)
    #pragma unroll
    for (int t = 0; t < 2; ++t) {
        unsigned hw[8];
        #pragma unroll
        for (int j = 0; j < 8; ++j)
            hw[j] = (unsigned)f2bf(h[t][2 * j]) | ((unsigned)f2bf(h[t][2 * j + 1]) << 16);
        unsigned* dst = (unsigned*)&hws[(t0 + 2 * ty + t) * DSLOT + d0];
        *(uint4*)dst = make_uint4(hw[0], hw[1], hw[2], hw[3]);
        *((uint4*)dst + 1) = make_uint4(hw[4], hw[5], hw[6], hw[7]);
    }
}

// ------------------------------------------------------------------
// Per-batch-row: masked softmax -> attnW, top-8 (stable, lower-idx tie-break),
// sel = h_sel@W2 + b2, ctx = (attnW . h)@W2 + b2.
// Register-resident candidates + wave shfl reductions: ~18 barriers total
// (baseline had ~90 via barrier-trees).
// ------------------------------------------------------------------
__global__ __launch_bounds__(256) void attn_kernel(
    const float* __restrict__ scores, const float* __restrict__ mask,
    const unsigned short* __restrict__ hws,
    const float* __restrict__ W2, const float* __restrict__ b2,
    float* __restrict__ out_sel, float* __restrict__ out_ctx, float* __restrict__ out_attn)
{
    const int b = blockIdx.x, tid = threadIdx.x;
    const int lane = tid & 63, wv = tid >> 6;     // 4 waves of 64

    __shared__ float ex[SS];                      // attn weights
    __shared__ float W2s[64][64];                 // 16 KB
    __shared__ float b2s[64];
    __shared__ float hselF[TOPK][64];
    __shared__ float cpart[16][65];               // ctx partials (pad 65 vs bank conflicts)
    __shared__ float ctxh[64];
    __shared__ float wredA[4], wredB[4];
    __shared__ float rv[4];
    __shared__ int   ri[4];
    __shared__ int   selIdx[TOPK];
    __shared__ int   anyv;

    // one-time stages
    for (int i = tid; i < 64 * 64; i += 256) W2s[i >> 6][i & 63] = W2[i];
    if (tid < 64) b2s[tid] = b2[tid];
    if (tid == 0) anyv = 0;
    __syncthreads();

    const float* srow = scores + (long)b * SS;
    const float* mrow = mask + (long)b * SS;

    // each thread owns indices i_k = tid + 256k, candidates in registers
    float tv[4];
    int localAny = 0;
    #pragma unroll
    for (int k = 0; k < 4; ++k) {
        int i = tid + k * 256;
        bool valid = mrow[i] > 0.5f;
        tv[k] = valid ? srow[i] : -__builtin_inff();
        if (valid) localAny = 1;
    }
    if (localAny) atomicOr(&anyv, 1);
    __syncthreads();
    const int av = anyv;
    if (!av) { tv[0] = 0.f; tv[1] = 0.f; tv[2] = 0.f; tv[3] = 0.f; }

    // row max: wave shfl reduce -> 4 partials -> broadcast
    float m = fmaxf(fmaxf(tv[0], tv[1]), fmaxf(tv[2], tv[3]));
    #pragma unroll
    for (int off = 32; off > 0; off >>= 1) m = fmaxf(m, __shfl_xor(m, off));
    if (lane == 0) wredA[wv] = m;
    __syncthreads();
    const float M = fmaxf(fmaxf(wredA[0], wredA[1]), fmaxf(wredA[2], wredA[3]));

    // exp + sum
    float e[4];
    float s = 0.f;
    #pragma unroll
    for (int k = 0; k < 4; ++k) { e[k] = expf(tv[k] - M); s += e[k]; }   // -inf -> 0
    #pragma unroll
    for (int off = 32; off > 0; off >>= 1) s += __shfl_xor(s, off);
    if (lane == 0) wredB[wv] = s;
    __syncthreads();
    const float invZ = 1.f / (wredB[0] + wredB[1] + wredB[2] + wredB[3]);
    #pragma unroll
    for (int k = 0; k < 4; ++k) {
        int i = tid + k * 256;
        float w = e[k] * invZ;
        ex[i] = w;
        out_attn[(long)b * SS + i] = w;
    }

    // top-8: register candidates, wave argmax, (higher val, then lower idx)
    unsigned usedm = 0;
    for (int r = 0; r < TOPK; ++r) {
        float bv = -__builtin_inff(); int bi = 0x7fffffff;
        #pragma unroll
        for (int k = 0; k < 4; ++k) {
            if (!(usedm & (1u << k))) {
                float v = tv[k]; int i = tid + k * 256;
                if (v > bv || (v == bv && i < bi)) { bv = v; bi = i; }
            }
        }
        #pragma unroll
        for (int off = 32; off > 0; off >>= 1) {
            float ov = __shfl_xor(bv, off); int oi = __shfl_xor(bi, off);
            if (ov > bv || (ov == bv && oi < bi)) { bv = ov; bi = oi; }
        }
        if (lane == 0) { rv[wv] = bv; ri[wv] = bi; }
        __syncthreads();
        float cv = rv[0]; int ci = ri[0];
        #pragma unroll
        for (int w = 1; w < 4; ++w) {
            if (rv[w] > cv || (rv[w] == cv && ri[w] < ci)) { cv = rv[w]; ci = ri[w]; }
        }
        if (tid == 0) selIdx[r] = ci;
        if ((ci & 255) == tid) usedm |= 1u << (ci >> 8);   // owner marks used
        __syncthreads();                                    // protect rv/ri reuse
    }

    // sel: load 8 selected h rows (bf16) -> LDS fp32
    {
        int r = tid >> 5, cp = tid & 31;   // 8 rows x 32 uint (2 ch each) = 256 threads
        unsigned u = *(const unsigned*)&hws[((long)b * SS + selIdx[r]) * DSLOT + cp * 2];
        hselF[r][cp * 2 + 0] = bf2f(u & 0xffffu);
        hselF[r][cp * 2 + 1] = bf2f(u >> 16);
    }
    __syncthreads();
    // sel = h_sel @ W2 + b2 : 512 outputs, 2 per thread
    #pragma unroll
    for (int o = 0; o < 2; ++o) {
        int f = tid + o * 256;
        int r = f >> 6, d = f & 63;
        float acc = b2s[d];
        #pragma unroll
        for (int j = 0; j < 64; ++j) acc = fmaf(hselF[r][j], W2s[j][d], acc);
        out_sel[(long)b * (TOPK * DSLOT) + f] = acc;
    }

    // ctx: ctxh = sum_s w_s * h_s  (thread: sg = tid>>4 slots, dg = tid&15 -> 4 ch)
    const int dg = tid & 15, sg = tid >> 4;
    float a0 = 0.f, a1 = 0.f, a2 = 0.f, a3 = 0.f;
    #pragma unroll 4
    for (int it = 0; it < 64; ++it) {
        int ss = sg * 64 + it;
        uint2 u = *(const uint2*)&hws[((long)b * SS + ss) * DSLOT + dg * 4];
        float w = ex[ss];
        a0 = fmaf(w, bf2f(u.x & 0xffffu), a0);
        a1 = fmaf(w, bf2f(u.x >> 16), a1);
        a2 = fmaf(w, bf2f(u.y & 0xffffu), a2);
        a3 = fmaf(w, bf2f(u.y >> 16), a3);
    }
    cpart[sg][dg * 4 + 0] = a0;
    cpart[sg][dg * 4 + 1] = a1;
    cpart[sg][dg * 4 + 2] = a2;
    cpart[sg][dg * 4 + 3] = a3;
    __syncthreads();
    if (tid < 64) {
        float acc = 0.f;
        #pragma unroll
        for (int g = 0; g < 16; ++g) acc += cpart[g][tid];
        ctxh[tid] = acc;
    }
    __syncthreads();
    // ctx = ctxh @ W2 + b2 (valid since sum_s w_s = 1)
    if (tid < 64) {
        float acc = b2s[tid];
        #pragma unroll
        for (int j = 0; j < 64; ++j) acc = fmaf(ctxh[j], W2s[j][tid], acc);
        out_ctx[(long)b * DSLOT + tid] = acc;
    }
}

// ------------------------------------------------------------------
extern "C" void kernel_launch(void* const* d_in, const int* in_sizes, int n_in,
                              void* d_out, int out_size, void* d_ws, size_t ws_size,
                              hipStream_t stream) {
    (void)in_sizes; (void)n_in; (void)out_size; (void)ws_size;
    const float* feats = (const float*)d_in[0];
    const float* smask = (const float*)d_in[1];
    const float* W1 = (const float*)d_in[2];
    const float* b1 = (const float*)d_in[3];
    const float* W2 = (const float*)d_in[4];
    const float* b2 = (const float*)d_in[5];
    const float* q  = (const float*)d_in[6];
    // d_in[7] = k (always 8)

    // workspace layout: h bf16 [1M x 64] (128 MB) | scores f32 [1M] (4 MB) | v[65]
    char* ws = (char*)d_ws;
    unsigned short* hws = (unsigned short*)ws;
    float* scores = (float*)(ws + (size_t)TOKENS * DSLOT * 2);
    float* vv = (float*)(ws + (size_t)TOKENS * DSLOT * 2 + (size_t)TOKENS * 4);

    float* out_sel  = (float*)d_out;                       // [1024, 8, 64]
    float* out_ctx  = out_sel + (long)BB * TOPK * DSLOT;   // [1024, 64]
    float* out_attn = out_ctx + (long)BB * DSLOT;          // [1024, 1024]

    prep_kernel<<<1, 64, 0, stream>>>(W2, b2, q, vv);
    mlp_kernel<<<TOKENS / TM, 256, 0, stream>>>(feats, W1, b1, vv, hws, scores);
    attn_kernel<<<BB, 256, 0, stream>>>(scores, smask, hws, W2, b2, out_sel, out_ctx, out_attn);
}